// Round 1
// baseline (153.750 us; speedup 1.0000x reference)
//
#include <hip/hip_runtime.h>
#include <cstdint>
#include <cstddef>

// Problem constants (B_, S, I, H) = (16, 2048, 256, 512)
#define BB 16
#define SS 2048
#define II 256
#define HH 512
#define MM (BB * SS)   /* 32768 GEMM rows            */
#define NN (2 * HH)    /* 1024 GEMM cols (re||im)    */
#define CHUNK 32       /* scan chunk length          */
#define NCHUNK (SS / CHUNK) /* 64 chunks per batch   */

using bf16x8 = __attribute__((ext_vector_type(8))) short;
using f32x4  = __attribute__((ext_vector_type(4))) float;

__device__ __forceinline__ short f2bf(float f) {
    uint32_t u = __float_as_uint(f);
    u += 0x7fffu + ((u >> 16) & 1u);   // round-to-nearest-even
    return (short)(u >> 16);
}

// ---- convert x (f32) -> bf16, 4 elems/thread, exact grid ----
__global__ __launch_bounds__(256) void cvt_x_kernel(const float4* __restrict__ x,
                                                    short4* __restrict__ xb) {
    int i = blockIdx.x * 256 + threadIdx.x;   // 2,097,152 threads exactly
    float4 v = x[i];
    short4 o;
    o.x = f2bf(v.x); o.y = f2bf(v.y); o.z = f2bf(v.z); o.w = f2bf(v.w);
    xb[i] = o;
}

// ---- pack B_re (rows 0..511) and B_im (rows 512..1023) -> bf16 [1024][256] ----
__global__ __launch_bounds__(256) void cvt_b_kernel(const float* __restrict__ Bre,
                                                    const float* __restrict__ Bim,
                                                    short* __restrict__ Bc) {
    int i = blockIdx.x * 256 + threadIdx.x;   // 262,144 threads exactly
    float v = (i < HH * II) ? Bre[i] : Bim[i - HH * II];
    Bc[i] = f2bf(v);
}

// ---- GEMM: Out[m][n] = sum_k Xb[m][k] * Bc[n][k]  (f32 out, bf16 in) ----
// 128x128 tile per block, 4 waves in 2x2, each wave 64x64 = 4x4 MFMA frags.
// Fragments loaded directly from global (L2-resident; K=256 only).
__global__ __launch_bounds__(256) void gemm_kernel(const short* __restrict__ Xb,
                                                   const short* __restrict__ Bc,
                                                   float* __restrict__ Out) {
    const int mt = blockIdx.x >> 3;          // 256 M-tiles
    const int nt = blockIdx.x & 7;           // 8 N-tiles
    const int m0 = mt * 128, n0 = nt * 128;
    const int w  = threadIdx.x >> 6;
    const int l  = threadIdx.x & 63;
    const int wr = w >> 1, wc = w & 1;       // 2x2 wave grid
    const int lr = l & 15;                   // frag row/col within 16
    const int lg = l >> 4;                   // k-group (0..3)

    f32x4 acc[4][4] = {};

    const short* Ab = Xb + (size_t)(m0 + wr * 64 + lr) * II + lg * 8;
    const short* Bb = Bc + (size_t)(n0 + wc * 64 + lr) * II + lg * 8;

#pragma unroll
    for (int kk = 0; kk < 8; ++kk) {         // K = 8 * 32
        bf16x8 a[4], b[4];
#pragma unroll
        for (int i = 0; i < 4; ++i)
            a[i] = *(const bf16x8*)(Ab + (size_t)i * 16 * II + kk * 32);
#pragma unroll
        for (int i = 0; i < 4; ++i)
            b[i] = *(const bf16x8*)(Bb + (size_t)i * 16 * II + kk * 32);
#pragma unroll
        for (int mi = 0; mi < 4; ++mi)
#pragma unroll
            for (int ni = 0; ni < 4; ++ni)
                acc[mi][ni] = __builtin_amdgcn_mfma_f32_16x16x32_bf16(
                    a[mi], b[ni], acc[mi][ni], 0, 0, 0);
    }

    // D layout: col = lane&15, row = (lane>>4)*4 + reg   [verified m89]
#pragma unroll
    for (int mi = 0; mi < 4; ++mi)
#pragma unroll
        for (int ni = 0; ni < 4; ++ni) {
            const size_t row0 = (size_t)(m0 + wr * 64 + mi * 16 + lg * 4);
            const int    col  = n0 + wc * 64 + ni * 16 + lr;
#pragma unroll
            for (int r = 0; r < 4; ++r)
                Out[(row0 + r) * NN + col] = acc[mi][ni][r];
        }
}

// ---- scan pass A: per-chunk local scan (h0 = 0), emit chunk-end state E ----
__global__ __launch_bounds__(512) void scan_partial(const float* __restrict__ Bx,
                                                    const float* __restrict__ nu,
                                                    const float* __restrict__ th,
                                                    float2* __restrict__ E) {
    const int b = blockIdx.x >> 6;     // 16
    const int c = blockIdx.x & 63;     // 64 chunks
    const int h = threadIdx.x;         // 512
    const float mod = __expf(-__expf(nu[h]));
    const float lre = mod * __cosf(th[h]);
    const float lim = mod * __sinf(th[h]);
    float hre = 0.f, him = 0.f;
    const float* base = Bx + ((size_t)b * SS + (size_t)c * CHUNK) * NN;
#pragma unroll 8
    for (int t = 0; t < CHUNK; ++t) {
        const float vre = base[(size_t)t * NN + h];
        const float vim = base[(size_t)t * NN + HH + h];
        const float nre = lre * hre - lim * him + vre;
        const float nim = lre * him + lim * hre + vim;
        hre = nre; him = nim;
    }
    E[((size_t)b * NCHUNK + c) * HH + h] = make_float2(hre, him);
}

// ---- scan pass B: sequential carry across chunks; P[c] = state entering chunk c ----
__global__ __launch_bounds__(512) void scan_carry(const float2* __restrict__ E,
                                                  const float* __restrict__ nu,
                                                  const float* __restrict__ th,
                                                  float2* __restrict__ P) {
    const int b = blockIdx.x;          // 16
    const int h = threadIdx.x;         // 512
    const float en  = __expf(nu[h]);
    const float rL  = __expf(-(float)CHUNK * en);        // |lam|^CHUNK
    const float aL  = (float)CHUNK * th[h];
    const float lre = rL * __cosf(aL);
    const float lim = rL * __sinf(aL);
    float pre = 0.f, pim = 0.f;
    for (int c = 0; c < NCHUNK; ++c) {
        const size_t idx = ((size_t)b * NCHUNK + c) * HH + h;
        P[idx] = make_float2(pre, pim);
        const float2 e = E[idx];
        const float nre = lre * pre - lim * pim + e.x;
        const float nim = lre * pim + lim * pre + e.y;
        pre = nre; pim = nim;
    }
}

// ---- scan pass C: final scan with carry, in-place over d_out ----
__global__ __launch_bounds__(512) void scan_final(const float2* __restrict__ P,
                                                  const float* __restrict__ nu,
                                                  const float* __restrict__ th,
                                                  float* __restrict__ Out) {
    const int b = blockIdx.x >> 6;
    const int c = blockIdx.x & 63;
    const int h = threadIdx.x;
    const float mod = __expf(-__expf(nu[h]));
    const float lre = mod * __cosf(th[h]);
    const float lim = mod * __sinf(th[h]);
    const float2 p = P[((size_t)b * NCHUNK + c) * HH + h];
    float hre = p.x, him = p.y;
    float* base = Out + ((size_t)b * SS + (size_t)c * CHUNK) * NN;
#pragma unroll 8
    for (int t = 0; t < CHUNK; ++t) {
        const float vre = base[(size_t)t * NN + h];
        const float vim = base[(size_t)t * NN + HH + h];
        const float nre = lre * hre - lim * him + vre;
        const float nim = lre * him + lim * hre + vim;
        hre = nre; him = nim;
        base[(size_t)t * NN + h]      = hre;
        base[(size_t)t * NN + HH + h] = him;
    }
}

extern "C" void kernel_launch(void* const* d_in, const int* in_sizes, int n_in,
                              void* d_out, int out_size, void* d_ws, size_t ws_size,
                              hipStream_t stream) {
    const float* x   = (const float*)d_in[0];
    const float* nu  = (const float*)d_in[1];
    const float* th  = (const float*)d_in[2];
    const float* Bre = (const float*)d_in[3];
    const float* Bim = (const float*)d_in[4];
    float* out = (float*)d_out;

    // ws layout: Xb bf16 [32768][256] (16 MiB) | Bc bf16 [1024][256] (512 KiB)
    //            | E float2 [16][64][512] (4 MiB) | P float2 (4 MiB)  => ~24.5 MiB
    char*  ws  = (char*)d_ws;
    short* Xb  = (short*)ws;
    short* Bc  = (short*)(ws + (size_t)MM * II * 2);
    float2* E  = (float2*)(ws + (size_t)MM * II * 2 + (size_t)NN * II * 2);
    float2* P  = E + (size_t)BB * NCHUNK * HH;

    cvt_x_kernel<<<(MM * II / 4) / 256, 256, 0, stream>>>((const float4*)x, (short4*)Xb);
    cvt_b_kernel<<<(NN * II) / 256, 256, 0, stream>>>(Bre, Bim, Bc);
    gemm_kernel<<<(MM / 128) * (NN / 128), 256, 0, stream>>>(Xb, Bc, out);
    scan_partial<<<BB * NCHUNK, HH, 0, stream>>>(out, nu, th, E);
    scan_carry<<<BB, HH, 0, stream>>>(E, nu, th, P);
    scan_final<<<BB * NCHUNK, HH, 0, stream>>>(P, nu, th, out);
}